// Round 1
// 1971.418 us; speedup vs baseline: 4.6110x; 4.6110x over previous
//
#include <hip/hip_runtime.h>

// FastGRNN: T=512 B=256 D=256 H=1024 RW=RU=64, fp32.
//   prep_kernel: one-time transposes W1->W1t[D][RW], W2->W2t[RW][H], U2->U2t[RU][H]
//                into workspace so all steady-state weight streams are lane-coalesced.
//   wx_kernel  : out[m, :] = (x[m,:] @ W1^T) @ W2^T, coalesced weight reads,
//                64-VGPR accumulator tile, ~FMA-issue-bound.
//   rec_kernel : 256 WGs x 1024 threads, 1 batch row per WG (4 waves/SIMD).
//                U1 in registers (rank-per-lane, h-seg-per-wave), U2 ranks 0..31
//                in LDS, ranks 32..63 streamed coalesced from U2t (L2-hot),
//                wx prefetched at loop top, h and biases in registers.

constexpr int T_ = 512;
constexpr int B_ = 256;
constexpr int D_ = 256;
constexpr int H_ = 1024;
constexpr int RW_ = 64;
constexpr int RU_ = 64;
constexpr int M_ = T_ * B_;
constexpr int ROWS = 16;  // x-rows per workgroup in wx_kernel

// workspace layout (floats)
constexpr size_t OFF_W1T = 0;                              // [D_][RW_]
constexpr size_t OFF_W2T = OFF_W1T + (size_t)D_ * RW_;     // [RW_][H_]
constexpr size_t OFF_U2T = OFF_W2T + (size_t)RW_ * H_;     // [RU_][H_]

__device__ __forceinline__ float sigmoid_f(float v) {
    v = fminf(fmaxf(v, -30.f), 30.f);
    return 1.f / (1.f + __expf(-v));
}
__device__ __forceinline__ float tanh_f(float v) {
    v = fminf(fmaxf(v, -15.f), 15.f);
    const float e2 = __expf(2.f * v);
    return (e2 - 1.f) / (e2 + 1.f);
}

__global__ __launch_bounds__(256) void prep_kernel(
    const float* __restrict__ W1, const float* __restrict__ W2,
    const float* __restrict__ U2, float* __restrict__ ws)
{
    const int tid = blockIdx.x * 256 + threadIdx.x;
    if (tid < D_ * RW_) {                 // W1t[d][r] = W1[r][d]
        const int d = tid >> 6, r = tid & 63;
        ws[OFF_W1T + tid] = W1[(size_t)r * D_ + d];
    }
    if (tid < RW_ * H_) {                 // W2t[r][j] = W2[j][r]; U2t[r][j] = U2[j][r]
        const int r = tid >> 10, j = tid & 1023;
        ws[OFF_W2T + tid] = W2[(size_t)j * RW_ + r];
        ws[OFF_U2T + tid] = U2[(size_t)j * RU_ + r];
    }
}

__global__ __launch_bounds__(256) void wx_kernel(
    const float* __restrict__ x, const float* __restrict__ ws,
    float* __restrict__ out)
{
    const float* __restrict__ W1t = ws + OFF_W1T;  // [D_][RW_]
    const float* __restrict__ W2t = ws + OFF_W2T;  // [RW_][H_]
    __shared__ __align__(16) float xs[ROWS][D_ + 4];      // pad 260: 2-way max
    __shared__ __align__(16) float xw1s[RW_][ROWS + 4];   // [64][20], bcast reads

    const int tid = threadIdx.x;
    const int m0 = blockIdx.x * ROWS;

    // stage x tile (16 x 256) coalesced
    {
        const float4* xg = (const float4*)(x + (size_t)m0 * D_);
#pragma unroll
        for (int k = 0; k < 4; ++k) {
            const int idx = tid + 256 * k;
            *(float4*)&xs[idx >> 6][(idx & 63) * 4] = xg[idx];
        }
    }
    __syncthreads();

    // phase A: thread (rowp = tid>>4, r4 = tid&15) -> xw1[rowp][4r4..4r4+3]
    // W1t reads: 16 lanes x 16B contiguous per instr (coalesced, L2-hot)
    {
        const int r4 = tid & 15, rowp = tid >> 4;
        float4 acc = {0.f, 0.f, 0.f, 0.f};
        const float* w1p = W1t + r4 * 4;
#pragma unroll 4
        for (int d4 = 0; d4 < D_ / 4; ++d4) {
            const float4 xv = *(const float4*)&xs[rowp][d4 * 4];
            const float4 w0 = *(const float4*)&w1p[(d4 * 4 + 0) * RW_];
            const float4 w1 = *(const float4*)&w1p[(d4 * 4 + 1) * RW_];
            const float4 w2 = *(const float4*)&w1p[(d4 * 4 + 2) * RW_];
            const float4 w3 = *(const float4*)&w1p[(d4 * 4 + 3) * RW_];
            acc.x += xv.x * w0.x + xv.y * w1.x + xv.z * w2.x + xv.w * w3.x;
            acc.y += xv.x * w0.y + xv.y * w1.y + xv.z * w2.y + xv.w * w3.y;
            acc.z += xv.x * w0.z + xv.y * w1.z + xv.z * w2.z + xv.w * w3.z;
            acc.w += xv.x * w0.w + xv.y * w1.w + xv.z * w2.w + xv.w * w3.w;
        }
        xw1s[r4 * 4 + 0][rowp] = acc.x;
        xw1s[r4 * 4 + 1][rowp] = acc.y;
        xw1s[r4 * 4 + 2][rowp] = acc.z;
        xw1s[r4 * 4 + 3][rowp] = acc.w;
    }
    __syncthreads();

    // phase B: thread owns 4 consecutive j; W2t row reads fully coalesced,
    // xw1 via LDS b128 broadcast; 16 float4 accumulators.
    {
        const int j0 = tid * 4;
        float4 acc[ROWS];
#pragma unroll
        for (int p = 0; p < ROWS; ++p) acc[p] = {0.f, 0.f, 0.f, 0.f};
#pragma unroll 4
        for (int r = 0; r < RW_; ++r) {
            const float4 wv = *(const float4*)&W2t[(size_t)r * H_ + j0];
            const float4 x0 = *(const float4*)&xw1s[r][0];
            const float4 x1 = *(const float4*)&xw1s[r][4];
            const float4 x2 = *(const float4*)&xw1s[r][8];
            const float4 x3 = *(const float4*)&xw1s[r][12];
#define FMA4(A, S) { (A).x += (S) * wv.x; (A).y += (S) * wv.y; (A).z += (S) * wv.z; (A).w += (S) * wv.w; }
            FMA4(acc[0], x0.x) FMA4(acc[1], x0.y) FMA4(acc[2], x0.z) FMA4(acc[3], x0.w)
            FMA4(acc[4], x1.x) FMA4(acc[5], x1.y) FMA4(acc[6], x1.z) FMA4(acc[7], x1.w)
            FMA4(acc[8], x2.x) FMA4(acc[9], x2.y) FMA4(acc[10], x2.z) FMA4(acc[11], x2.w)
            FMA4(acc[12], x3.x) FMA4(acc[13], x3.y) FMA4(acc[14], x3.z) FMA4(acc[15], x3.w)
#undef FMA4
        }
        float* op = out + (size_t)m0 * H_ + j0;
#pragma unroll
        for (int p = 0; p < ROWS; ++p)
            *(float4*)&op[(size_t)p * H_] = acc[p];
    }
}

__global__ __launch_bounds__(1024) void rec_kernel(
    const float* __restrict__ h0, const float* __restrict__ U1,
    const float* __restrict__ U2, const float* __restrict__ ws,
    const float* __restrict__ bg, const float* __restrict__ bu,
    const float* __restrict__ zeta, const float* __restrict__ nu,
    float* __restrict__ out)
{
    __shared__ __align__(16) float hs[H_];          // 4 KB   current h row
    __shared__ float part[16][RU_ + 1];             // 4.1 KB phase-1 partials (pad 65)
    __shared__ __align__(16) float uh1f[RU_];       // 256 B  reduced uh1
    __shared__ float4 u2l[8][H_];                   // 128 KB u2l[r4][j] = U2[j][4r4..4r4+3]

    const int tid = threadIdx.x;
    const int b = blockIdx.x;
    const int lane = tid & 63;   // rank
    const int wv = tid >> 6;     // h-segment (wave id, 0..15)
    const int j = tid;           // owned h/output column

    // one-time: U2 ranks 0..31 into LDS (row-j reads, uncoalesced but once)
    {
        const float4* u2row = (const float4*)(U2 + (size_t)j * RU_);
#pragma unroll
        for (int r4 = 0; r4 < 8; ++r4) u2l[r4][j] = u2row[r4];
    }
    // one-time: U1 rank `lane`, h-window [wv*64, wv*64+64) into 16 float4 regs
    float4 u1reg[16];
    {
        const float4* u1p = (const float4*)(U1 + (size_t)lane * H_ + wv * 64);
#pragma unroll
        for (int i = 0; i < 16; ++i) u1reg[i] = u1p[i];
    }
    float hreg = h0[(size_t)b * H_ + j];
    hs[j] = hreg;
    const float bgr = bg[j];
    const float bur = bu[j];
    const float zs = 1.f / (1.f + __expf(-zeta[0]));
    const float ns = 1.f / (1.f + __expf(-nu[0]));
    __syncthreads();

    const size_t BH = (size_t)B_ * H_;
    float* outp = out + (size_t)b * H_ + j;                  // wx in, h out (in-place)
    const float* u2s = ws + OFF_U2T + (size_t)32 * H_ + j;   // streamed ranks 32..63

    for (int t = 0; t < T_; ++t, outp += BH) {
        const float wxv = *outp;  // prefetch: consumed after phase 2

        // phase 1: partial uh1[lane] over this wave's h-window (U1 from regs,
        // hs via b128 broadcast — conflict-free)
        float a1 = 0.f;
#pragma unroll
        for (int i = 0; i < 16; ++i) {
            const float4 hv = *(const float4*)&hs[wv * 64 + i * 4];
            const float4 u = u1reg[i];
            a1 += hv.x * u.x + hv.y * u.y + hv.z * u.z + hv.w * u.w;
        }
        part[wv][lane] = a1;
        __syncthreads();

        if (tid < RU_) {  // wave 0 (uniform): reduce 16 segments
            float s = 0.f;
#pragma unroll
            for (int w = 0; w < 16; ++w) s += part[w][tid];
            uh1f[tid] = s;
        }
        __syncthreads();

        // phase 2: uh[j] = sum_r uh1[r] * U2[j][r]
        float acc = 0.f;
#pragma unroll
        for (int r4 = 0; r4 < 8; ++r4) {          // ranks 0..31 from LDS
            const float4 uh = *(const float4*)&uh1f[r4 * 4];
            const float4 u2 = u2l[r4][j];
            acc += uh.x * u2.x + uh.y * u2.y + uh.z * u2.z + uh.w * u2.w;
        }
#pragma unroll
        for (int r4 = 0; r4 < 8; ++r4) {          // ranks 32..63 streamed, coalesced
            const float4 uh = *(const float4*)&uh1f[32 + r4 * 4];
            const float* p = u2s + (size_t)(r4 * 4) * H_;
            acc += uh.x * p[0] + uh.y * p[H_] + uh.z * p[2 * H_] + uh.w * p[3 * H_];
        }

        // elementwise gate/update
        const float pre = wxv + acc;
        const float zg = sigmoid_f(pre + bgr);
        const float c = tanh_f(pre + bur);
        const float hn = (zs * (1.f - zg) + ns) * c + zg * hreg;
        *outp = hn;
        hreg = hn;
        hs[j] = hn;
        __syncthreads();
    }
}

extern "C" void kernel_launch(void* const* d_in, const int* in_sizes, int n_in,
                              void* d_out, int out_size, void* d_ws, size_t ws_size,
                              hipStream_t stream) {
    const float* x = (const float*)d_in[0];
    const float* h0 = (const float*)d_in[1];
    const float* W1 = (const float*)d_in[2];
    const float* W2 = (const float*)d_in[3];
    const float* U1 = (const float*)d_in[4];
    const float* U2 = (const float*)d_in[5];
    const float* bg = (const float*)d_in[6];
    const float* bu = (const float*)d_in[7];
    const float* zeta = (const float*)d_in[8];
    const float* nu = (const float*)d_in[9];
    float* out = (float*)d_out;
    float* ws = (float*)d_ws;  // needs (D*RW + 2*RW*H)*4 = 590 KB

    prep_kernel<<<RW_ * H_ / 256, 256, 0, stream>>>(W1, W2, U2, ws);
    wx_kernel<<<M_ / ROWS, 256, 0, stream>>>(x, ws, out);
    rec_kernel<<<B_, 1024, 0, stream>>>(h0, U1, U2, ws, bg, bu, zeta, nu, out);
}